// Round 7
// baseline (334.278 us; speedup 1.0000x reference)
//
#include <hip/hip_runtime.h>
#include <hip/hip_bf16.h>
#include <math.h>

#define Bn 64
#define Sn 512
#define Hn 1024
#define Tn 48

#define LOG2E 1.4426950408889634f
#define LN2f  0.6931471805599453f

#define PRED_OFF (Bn*Sn*Tn)
#define LOSS_OFF (PRED_OFF + Bn*Sn)

#define RL(x,i) __int_as_float(__builtin_amdgcn_readlane(__float_as_int(x),(i)))

#if __has_builtin(__builtin_amdgcn_exp2f)
#define EXP2(x) __builtin_amdgcn_exp2f(x)
#else
#define EXP2(x) exp2f(x)
#endif
#if __has_builtin(__builtin_amdgcn_logf)
#define LOG2(x) __builtin_amdgcn_logf(x)
#else
#define LOG2(x) log2f(x)
#endif

__device__ __forceinline__ unsigned umin2(unsigned a, unsigned b) { return a < b ? a : b; }

// ======================= GEMM: feat = x @ W + b =======================
// BM=128, 256 threads = 4 waves. Wave w owns cols 12w..12w+11 (wave-uniform
// -> W read via s_load, used as SGPR operand in v_fmac). x staged in LDS
// (stride 65, b32 reads 2-way = free). Per kk per thread: 2 LDS reads + 24 FMA.
__global__ __launch_bounds__(256) void gemm_feat(
    const float* __restrict__ x, const float* __restrict__ W,
    const float* __restrict__ bias, float* __restrict__ feat)
{
  __shared__ float xs[128][65];
  const int tid  = threadIdx.x;
  const int lane = tid & 63;
  const int col0 = __builtin_amdgcn_readfirstlane((tid >> 6) * 12);
  const size_t row0 = (size_t)blockIdx.x * 128;

  const int srow = tid >> 1;           // 0..127 staging row
  const int skk0 = (tid & 1) * 32;     // kk half base (in floats)

  const int r0 = lane;
  const int r1 = lane + 64;

  float4 xreg[8];
  #pragma unroll
  for (int p = 0; p < 8; ++p)
    xreg[p] = *reinterpret_cast<const float4*>(&x[(row0 + srow)*Hn + skk0 + p*4]);

  float acc0[12], acc1[12];
  #pragma unroll
  for (int c = 0; c < 12; ++c) { acc0[c] = 0.f; acc1[c] = 0.f; }

  for (int k0 = 0; k0 < Hn; k0 += 64) {
    #pragma unroll
    for (int p = 0; p < 8; ++p) {
      xs[srow][skk0 + p*4 + 0] = xreg[p].x;
      xs[srow][skk0 + p*4 + 1] = xreg[p].y;
      xs[srow][skk0 + p*4 + 2] = xreg[p].z;
      xs[srow][skk0 + p*4 + 3] = xreg[p].w;
    }
    __syncthreads();
    if (k0 + 64 < Hn) {
      #pragma unroll
      for (int p = 0; p < 8; ++p)
        xreg[p] = *reinterpret_cast<const float4*>(&x[(row0 + srow)*Hn + (k0+64) + skk0 + p*4]);
    }
    const float* Wk = W + (size_t)k0 * Tn + col0;   // uniform
    #pragma unroll 4
    for (int kk = 0; kk < 64; ++kk) {
      const float a0 = xs[r0][kk];
      const float a1 = xs[r1][kk];
      const float* wrow = Wk + kk * Tn;             // uniform -> s_load
      #pragma unroll
      for (int c = 0; c < 12; ++c) {
        const float wv_ = wrow[c];
        acc0[c] = fmaf(a0, wv_, acc0[c]);
        acc1[c] = fmaf(a1, wv_, acc1[c]);
      }
    }
    __syncthreads();
  }
  #pragma unroll
  for (int c = 0; c < 12; ++c) {
    const float bv = bias[col0 + c];
    feat[(row0 + r0)*Tn + col0 + c] = acc0[c] + bv;
    feat[(row0 + r1)*Tn + col0 + c] = acc1[c] + bv;
  }
}

// ======================= CRF: 192 single-wave blocks =======================
// role 0: log-partition (linear-space matvec, LDS-broadcast p, log2 rebased)
// role 1: Viterbi forward (LDS-broadcast v, early state write, flag-free
//         sign-bit-key argmax) + segment-parallel backtrace
// role 2: gold score
// Both scan roles use a depth-8 rolling emission prefetch queue.
__global__ __launch_bounds__(64, 1) void crf_kernel(
    const float* __restrict__ feat,
    const int* __restrict__ mask,
    const int* __restrict__ labels,
    const float* __restrict__ trans,
    const float* __restrict__ startv,
    const float* __restrict__ endv,
    float* __restrict__ pred_out,
    float* __restrict__ wsLogZ,
    float* __restrict__ wsGold)
{
  __shared__ unsigned char bpL[Sn * 64];     // 32 KB backpointers, stride 64
  __shared__ unsigned char pathL[384 * 64];  // 24 KB segment paths
  __shared__ __align__(16) float slds[64];   // state broadcast buffer
  __shared__ int EA[8];

  const int role = blockIdx.x >> 6;
  const int b    = blockIdx.x & 63;
  const int lane = threadIdx.x;
  const float* fb = feat + (size_t)b * Sn * Tn;

  // sequence length (mask is a prefix mask)
  int lc = 0;
  #pragma unroll
  for (int it = 0; it < Sn/64; ++it) lc += (mask[(size_t)b*Sn + it*64 + lane] != 0);
  #pragma unroll
  for (int off = 32; off; off >>= 1) lc += __shfl_xor(lc, off);
  const int len = lc;

  const int j = (lane < Tn) ? lane : (Tn - 1);
  const float4* sv4 = reinterpret_cast<const float4*>(slds);

  if (role == 0) {
    // ---------------- log-partition ----------------
    float Ev[48];
    #pragma unroll
    for (int i = 0; i < 48; ++i) Ev[i] = EXP2(trans[i*Tn + j] * LOG2E); // e^trans
    float emq[8];
    #pragma unroll
    for (int d = 0; d < 8; ++d) {
      int s = 1 + d; s = s < len ? s : len - 1;
      emq[d] = fb[(size_t)s * Tn + j];
    }
    const float a0 = (startv[j] + fb[j]) * LOG2E;
    float Zref = RL(a0, 0);
    float beta = a0 - Zref;                  // beta[0] == 0
    slds[lane] = EXP2(beta);
    for (int t = 1; t < len; t += 8) {
      #pragma unroll
      for (int u = 0; u < 8; ++u) {
        const int tt = t + u;
        if (tt < len) {
          const float em2 = emq[u] * LOG2E;
          int tf = tt + 8; tf = tf < len ? tf : len - 1;
          emq[u] = fb[(size_t)tf * Tn + j];
          float4 av[12];
          #pragma unroll
          for (int k = 0; k < 12; ++k) av[k] = sv4[k];   // broadcast reads
          float s0=0.f, s1=0.f, s2=0.f, s3=0.f;
          #pragma unroll
          for (int k = 0; k < 12; ++k) {
            s0 = fmaf(av[k].x, Ev[4*k+0], s0);
            s1 = fmaf(av[k].y, Ev[4*k+1], s1);
            s2 = fmaf(av[k].z, Ev[4*k+2], s2);
            s3 = fmaf(av[k].w, Ev[4*k+3], s3);
          }
          const float dj = LOG2((s0 + s1) + (s2 + s3)) + em2;
          const float d0 = RL(dj, 0);
          const float nb = dj - d0;
          slds[lane] = EXP2(nb);             // write after reads: in-wave order
          Zref += d0;
          beta = nb;
        }
      }
    }
    float fv = (lane < Tn) ? beta + endv[lane] * LOG2E : -INFINITY;
    float m = fv;
    #pragma unroll
    for (int off = 32; off; off >>= 1) m = fmaxf(m, __shfl_xor(m, off));
    float e = (lane < Tn) ? EXP2(fv - m) : 0.f;
    #pragma unroll
    for (int off = 32; off; off >>= 1) e += __shfl_xor(e, off);
    if (lane == 0) wsLogZ[b] = (Zref + m + LOG2(e)) * LN2f;

  } else if (role == 1) {
    // ---------------- Viterbi forward ----------------
    float trv[48];
    #pragma unroll
    for (int i = 0; i < 48; ++i) trv[i] = trans[i*Tn + j];
    float emq[8];
    #pragma unroll
    for (int d = 0; d < 8; ++d) {
      int s = 1 + d; s = s < len ? s : len - 1;
      emq[d] = fb[(size_t)s * Tn + j];
    }
    float v = startv[j] + fb[j];
    slds[lane] = v;
    for (int t = 1; t < len; t += 8) {
      #pragma unroll
      for (int u = 0; u < 8; ++u) {
        const int tt = t + u;
        if (tt < len) {
          const float em_cur = emq[u];
          int tf = tt + 8; tf = tf < len ? tf : len - 1;
          emq[u] = fb[(size_t)tf * Tn + j];
          float4 av[12];
          #pragma unroll
          for (int k = 0; k < 12; ++k) av[k] = sv4[k];   // broadcast reads
          float q[48];
          #pragma unroll
          for (int k = 0; k < 12; ++k) {
            q[4*k+0] = av[k].x + trv[4*k+0];
            q[4*k+1] = av[k].y + trv[4*k+1];
            q[4*k+2] = av[k].z + trv[4*k+2];
            q[4*k+3] = av[k].w + trv[4*k+3];
          }
          // value: max3 tree (flag-free)
          float m16[16];
          #pragma unroll
          for (int uu = 0; uu < 16; ++uu)
            m16[uu] = fmaxf(fmaxf(q[3*uu], q[3*uu+1]), q[3*uu+2]);
          float m6a = fmaxf(fmaxf(m16[0],  m16[1]),  m16[2]);
          float m6b = fmaxf(fmaxf(m16[3],  m16[4]),  m16[5]);
          float m6c = fmaxf(fmaxf(m16[6],  m16[7]),  m16[8]);
          float m6d = fmaxf(fmaxf(m16[9],  m16[10]), m16[11]);
          float m6e = fmaxf(fmaxf(m16[12], m16[13]), m16[14]);
          float m6f = m16[15];
          const float best = fmaxf(fmaxf(fmaxf(m6a,m6b),m6c),
                                   fmaxf(fmaxf(m6d,m6e),m6f));
          v = best + em_cur;
          slds[lane] = v;                    // EARLY write: index tree below
                                             // overlaps the LDS round trip
          // index: key = bits(q - best) | i ; ties -> key=i (sign bit clear).
          unsigned s16[16];
          #pragma unroll
          for (int uu = 0; uu < 16; ++uu) {
            const unsigned ka = __float_as_uint(q[3*uu]   - best) | (unsigned)(3*uu);
            const unsigned kb = __float_as_uint(q[3*uu+1] - best) | (unsigned)(3*uu+1);
            const unsigned kc = __float_as_uint(q[3*uu+2] - best) | (unsigned)(3*uu+2);
            s16[uu] = umin2(umin2(ka, kb), kc);
          }
          unsigned i6a = umin2(umin2(s16[0],  s16[1]),  s16[2]);
          unsigned i6b = umin2(umin2(s16[3],  s16[4]),  s16[5]);
          unsigned i6c = umin2(umin2(s16[6],  s16[7]),  s16[8]);
          unsigned i6d = umin2(umin2(s16[9],  s16[10]), s16[11]);
          unsigned i6e = umin2(umin2(s16[12], s16[13]), s16[14]);
          unsigned i6f = s16[15];
          const unsigned bidx = umin2(umin2(umin2(i6a,i6b),i6c), umin2(umin2(i6d,i6e),i6f));
          bpL[tt*64 + lane] = (unsigned char)bidx;
        }
      }
    }
    // identity backpointers for masked steps
    for (int t = len; t < Sn; ++t) bpL[t*64 + lane] = (unsigned char)lane;

    // final first-occurrence argmax across lanes
    float fv = (lane < Tn) ? v + endv[lane] : -INFINITY;
    int fi = (lane < Tn) ? lane : 64;
    #pragma unroll
    for (int off = 32; off; off >>= 1) {
      const float ov = __shfl_xor(fv, off);
      const int   oi = __shfl_xor(fi, off);
      if (ov > fv || (ov == fv && oi < fi)) { fv = ov; fi = oi; }
    }
    __syncthreads();

    // ---- segment-parallel backtrace: 8 segments x 48 entry tags = 384 jobs,
    //      6 interleaved chains per lane ----
    #define JOB(r) \
      const int id##r  = lane + 64*(r); \
      const int seg##r = id##r & 7;     \
      int cur##r = id##r >> 3;          \
      const int bpb##r = seg##r << 12;  \
      const int pb##r  = id##r << 6;    \
      pathL[pb##r + 63] = (unsigned char)cur##r;
    JOB(0) JOB(1) JOB(2) JOB(3) JOB(4) JOB(5)
    for (int d = 62; d >= 0; --d) {
      const int o = (d + 1) << 6;
      cur0 = bpL[bpb0 + o + cur0]; pathL[pb0 + d] = (unsigned char)cur0;
      cur1 = bpL[bpb1 + o + cur1]; pathL[pb1 + d] = (unsigned char)cur1;
      cur2 = bpL[bpb2 + o + cur2]; pathL[pb2 + d] = (unsigned char)cur2;
      cur3 = bpL[bpb3 + o + cur3]; pathL[pb3 + d] = (unsigned char)cur3;
      cur4 = bpL[bpb4 + o + cur4]; pathL[pb4 + d] = (unsigned char)cur4;
      cur5 = bpL[bpb5 + o + cur5]; pathL[pb5 + d] = (unsigned char)cur5;
    }
    #undef JOB
    __syncthreads();
    // stitch: E[s] = tag at position 64s+63
    if (lane == 0) {
      int Ecur = fi;                       // tag at 511 (identity-propagated)
      EA[7] = Ecur;
      for (int s = 7; s >= 1; --s) {
        const int bottom = pathL[((Ecur << 3) + s) * 64];   // tag at 64s
        Ecur = bpL[(s << 12) + bottom];                     // bp[64s][.] -> tag at 64s-1
        EA[s-1] = Ecur;
      }
    }
    __syncthreads();
    #pragma unroll
    for (int r8 = 0; r8 < 8; ++r8) {
      const int t = r8*64 + lane;
      const int pv = pathL[((EA[r8] << 3) + r8) * 64 + lane];
      pred_out[(size_t)b*Sn + t] = (t < len) ? (float)pv : 0.f;
    }

  } else {
    // ---------------- gold score ----------------
    float g = 0.f;
    #pragma unroll
    for (int it = 0; it < Sn/64; ++it) {
      const int sg = it*64 + lane;
      if (sg < len) {
        const int la = labels[(size_t)b*Sn + sg];
        float e = fb[(size_t)sg*Tn + la];
        if (sg > 0) e += trans[labels[(size_t)b*Sn + sg - 1]*Tn + la];
        g += e;
      }
    }
    #pragma unroll
    for (int off = 32; off; off >>= 1) g += __shfl_xor(g, off);
    if (lane == 0) {
      g += startv[labels[(size_t)b*Sn]] + endv[labels[(size_t)b*Sn + len - 1]];
      wsGold[b] = g;
    }
  }
}

__global__ void loss_reduce(const float* __restrict__ wsLogZ,
                            const float* __restrict__ wsGold,
                            float* __restrict__ out)
{
  const int lane = threadIdx.x;
  float v = wsLogZ[lane] - wsGold[lane];
  #pragma unroll
  for (int off = 32; off; off >>= 1) v += __shfl_xor(v, off);
  if (lane == 0) out[0] = v;
}

extern "C" void kernel_launch(void* const* d_in, const int* in_sizes, int n_in,
                              void* d_out, int out_size, void* d_ws, size_t ws_size,
                              hipStream_t stream) {
  const float* x      = (const float*)d_in[0];
  const int*   mask   = (const int*)  d_in[1];
  const int*   labels = (const int*)  d_in[2];
  const float* W      = (const float*)d_in[3];
  const float* bias   = (const float*)d_in[4];
  const float* trans  = (const float*)d_in[5];
  const float* startv = (const float*)d_in[6];
  const float* endv   = (const float*)d_in[7];

  float* out  = (float*)d_out;
  float* feat = out;                 // output 0: features [B][S][T]
  float* pred = out + PRED_OFF;      // output 1: pred_labels as float [B][S]
  float* loss = out + LOSS_OFF;      // output 2: scalar loss
  float* wsLogZ = (float*)d_ws;
  float* wsGold = wsLogZ + 64;

  gemm_feat<<<(Bn*Sn)/128, 256, 0, stream>>>(x, W, bias, feat);
  crf_kernel<<<192, 64, 0, stream>>>(feat, mask, labels, trans, startv, endv, pred, wsLogZ, wsGold);
  loss_reduce<<<1, 64, 0, stream>>>(wsLogZ, wsGold, loss);
}